// Round 1
// baseline (500.372 us; speedup 1.0000x reference)
//
#include <hip/hip_runtime.h>

// Problem constants (from reference)
#define TT    128   // T
#define CC    512   // C
#define HIDN  1024  // HID
#define HORN  96    // HOR
#define NB    256   // B
#define HT    128   // h-tile per block
#define KC    16    // k chunk staged in LDS
#define NCHUNK (CC / KC)  // 32
#define LDT   132   // padded LDS row stride (t dimension)
#define LDH   132   // padded LDS row stride (h dimension)

// Kernel A: fused proj GEMM (x @ W1^T) + leaky scan over T -> memT[b, h]
// grid = (HID/HT, B), block = 256
__global__ void __launch_bounds__(256)
snn_proj_scan(const float* __restrict__ x, const float* __restrict__ W1,
              const float* __restrict__ b1, const float* __restrict__ betap,
              float* __restrict__ memT)
{
    // transposed staging: xs[kk][t], ws[kk][h] so inner reads are contiguous float4
    __shared__ float xs[KC][LDT];
    __shared__ float ws[KC][LDH];
    __shared__ float sbuf[16][HT];   // scan bounce buffer: 16 t-rows x 128 h

    const int tid   = threadIdx.x;
    const int b     = blockIdx.y;
    const int hbase = blockIdx.x * HT;

    // thread's output sub-tile: 8 t-rows x 8 h-cols
    const int t0 = (tid >> 4) << 3;   // 0..120
    const int h0 = (tid & 15) << 3;   // 0..120

    const float* xg = x  + (size_t)b * TT * CC;
    const float* wg = W1 + (size_t)hbase * CC;

    // staging assignment: chunk = 128 rows x 16 c = 512 float4; 2 per thread
    const int r0 = tid >> 2,          k0 = tid & 3;
    const int r1 = (tid + 256) >> 2,  k1 = tid & 3;  // e1 = tid+256 -> same k, row+64

    float acc[8][8];
#pragma unroll
    for (int i = 0; i < 8; ++i)
#pragma unroll
        for (int j = 0; j < 8; ++j) acc[i][j] = 0.f;

    // prefetch chunk 0 into registers
    float4 px0 = *(const float4*)(xg + r0 * CC + k0 * 4);
    float4 px1 = *(const float4*)(xg + r1 * CC + k1 * 4);
    float4 pw0 = *(const float4*)(wg + r0 * CC + k0 * 4);
    float4 pw1 = *(const float4*)(wg + r1 * CC + k1 * 4);

    for (int ck = 0; ck < NCHUNK; ++ck) {
        // write prefetched registers to LDS (transposed)
        xs[k0 * 4 + 0][r0] = px0.x; xs[k0 * 4 + 1][r0] = px0.y;
        xs[k0 * 4 + 2][r0] = px0.z; xs[k0 * 4 + 3][r0] = px0.w;
        xs[k1 * 4 + 0][r1] = px1.x; xs[k1 * 4 + 1][r1] = px1.y;
        xs[k1 * 4 + 2][r1] = px1.z; xs[k1 * 4 + 3][r1] = px1.w;
        ws[k0 * 4 + 0][r0] = pw0.x; ws[k0 * 4 + 1][r0] = pw0.y;
        ws[k0 * 4 + 2][r0] = pw0.z; ws[k0 * 4 + 3][r0] = pw0.w;
        ws[k1 * 4 + 0][r1] = pw1.x; ws[k1 * 4 + 1][r1] = pw1.y;
        ws[k1 * 4 + 2][r1] = pw1.z; ws[k1 * 4 + 3][r1] = pw1.w;
        __syncthreads();

        // issue next chunk's loads; latency hides under compute below
        if (ck + 1 < NCHUNK) {
            const int cb = (ck + 1) * KC;
            px0 = *(const float4*)(xg + r0 * CC + cb + k0 * 4);
            px1 = *(const float4*)(xg + r1 * CC + cb + k1 * 4);
            pw0 = *(const float4*)(wg + r0 * CC + cb + k0 * 4);
            pw1 = *(const float4*)(wg + r1 * CC + cb + k1 * 4);
        }

#pragma unroll
        for (int kk = 0; kk < KC; ++kk) {
            const float4 a0 = *(const float4*)&xs[kk][t0];
            const float4 a1 = *(const float4*)&xs[kk][t0 + 4];
            const float4 w0 = *(const float4*)&ws[kk][h0];
            const float4 w1 = *(const float4*)&ws[kk][h0 + 4];
            const float ar[8] = {a0.x, a0.y, a0.z, a0.w, a1.x, a1.y, a1.z, a1.w};
            const float wr[8] = {w0.x, w0.y, w0.z, w0.w, w1.x, w1.y, w1.z, w1.w};
#pragma unroll
            for (int i = 0; i < 8; ++i)
#pragma unroll
                for (int j = 0; j < 8; ++j)
                    acc[i][j] = fmaf(ar[i], wr[j], acc[i][j]);
        }
        __syncthreads();
    }

    // ---- sequential leaky scan over t (snntorch Leaky, reset=subtract) ----
    const float beta_c = fminf(fmaxf(betap[0], 0.f), 1.f);
    float b1h = 0.f;
    if (tid < HT) b1h = b1[hbase + tid];
    float mem = 0.f;

    const int my_chunk = tid >> 5;     // which 16-t chunk this thread's rows fall in
    const int rbase    = t0 & 15;      // 0 or 8

    for (int q = 0; q < 8; ++q) {
        if (my_chunk == q) {
#pragma unroll
            for (int i = 0; i < 8; ++i) {
                float4 v0 = {acc[i][0], acc[i][1], acc[i][2], acc[i][3]};
                float4 v1 = {acc[i][4], acc[i][5], acc[i][6], acc[i][7]};
                *(float4*)&sbuf[rbase + i][h0]     = v0;
                *(float4*)&sbuf[rbase + i][h0 + 4] = v1;
            }
        }
        __syncthreads();
        if (tid < HT) {
#pragma unroll
            for (int tt = 0; tt < 16; ++tt) {
                const float inp   = sbuf[tt][tid] + b1h;
                const float reset = (mem > 1.0f) ? 1.0f : 0.0f; // strictly >, prev mem
                mem = beta_c * mem + inp - reset;
            }
        }
        __syncthreads();  // sbuf reused next q
    }

    if (tid < HT) memT[(size_t)b * HIDN + hbase + tid] = mem;
}

// Kernel B: out[b, o] = memT[b, :] . Wh[o, :] + bh[o]
// grid = B, block = 128 (threads 96..127 idle in the dot phase)
__global__ void __launch_bounds__(128)
snn_head(const float* __restrict__ memT, const float* __restrict__ Wh,
         const float* __restrict__ bh, float* __restrict__ out)
{
    __shared__ float ms[HIDN];
    const int b   = blockIdx.x;
    const int tid = threadIdx.x;

    // stage memT[b,:] (1024 floats) in LDS
    const float4* src = (const float4*)(memT + (size_t)b * HIDN);
#pragma unroll
    for (int p = 0; p < 2; ++p)
        ((float4*)ms)[p * 128 + tid] = src[p * 128 + tid];
    __syncthreads();

    if (tid < HORN) {
        const float4* wr = (const float4*)(Wh + (size_t)tid * HIDN);
        float sx = 0.f, sy = 0.f, sz = 0.f, sw = 0.f;
        for (int q = 0; q < HIDN / 4; ++q) {
            const float4 w = wr[q];
            const float4 m = ((const float4*)ms)[q];
            sx = fmaf(w.x, m.x, sx);
            sy = fmaf(w.y, m.y, sy);
            sz = fmaf(w.z, m.z, sz);
            sw = fmaf(w.w, m.w, sw);
        }
        out[(size_t)b * HORN + tid] = sx + sy + sz + sw + bh[tid];
    }
}

extern "C" void kernel_launch(void* const* d_in, const int* in_sizes, int n_in,
                              void* d_out, int out_size, void* d_ws, size_t ws_size,
                              hipStream_t stream)
{
    (void)in_sizes; (void)n_in; (void)out_size; (void)ws_size;
    const float* x    = (const float*)d_in[0];
    const float* W1   = (const float*)d_in[1];
    const float* b1   = (const float*)d_in[2];
    const float* Wh   = (const float*)d_in[3];
    const float* bh   = (const float*)d_in[4];
    const float* beta = (const float*)d_in[5];

    float* memT = (float*)d_ws;   // [B, HID] f32 = 1 MB scratch

    dim3 gridA(HIDN / HT, NB);    // (8, 256)
    snn_proj_scan<<<gridA, 256, 0, stream>>>(x, W1, b1, beta, memT);
    snn_head<<<NB, 128, 0, stream>>>(memT, Wh, bh, (float*)d_out);
}

// Round 2
// 237.484 us; speedup vs baseline: 2.1070x; 2.1070x over previous
//
#include <hip/hip_runtime.h>

#define TT 128
#define CC 512
#define HIDN 1024
#define HORN 96
#define NB 256
#define BM 128
#define BN 128
#define BK 64
#define NSTAGE 8

typedef _Float16 f16x8 __attribute__((ext_vector_type(8)));
typedef _Float16 f16x4 __attribute__((ext_vector_type(4)));
typedef float f32x16 __attribute__((ext_vector_type(16)));

// LDS layout: 4 staging tiles [128 rows][64 f16] (16 KB each, XOR-swizzled),
// later reused as scan buffer [128 h][132 t] f32.
#define XHI 0
#define XLO 16384
#define WHI 32768
#define WLO 49152
#define SMEM_BYTES 67584

// fp16 two-term split: v = hi + lo with |err| ~ 2^-22 * |v|.
// RTZ for hi is fine: residual (v - hi) is exact in f32, lo captures it.
__device__ __forceinline__ void cvt_split(const float4 v, f16x4* hi, f16x4* lo) {
    auto h01 = __builtin_amdgcn_cvt_pkrtz(v.x, v.y);
    auto h23 = __builtin_amdgcn_cvt_pkrtz(v.z, v.w);
    auto l01 = __builtin_amdgcn_cvt_pkrtz(v.x - (float)h01.x, v.y - (float)h01.y);
    auto l23 = __builtin_amdgcn_cvt_pkrtz(v.z - (float)h23.x, v.w - (float)h23.y);
    *hi = (f16x4){(_Float16)h01.x, (_Float16)h01.y, (_Float16)h23.x, (_Float16)h23.y};
    *lo = (f16x4){(_Float16)l01.x, (_Float16)l01.y, (_Float16)l23.x, (_Float16)l23.y};
}

// Fused: proj = x @ W1^T (split-f16 MFMA) then leaky scan over T -> memT[b,h]
// grid = 2048 (8 h-tiles x 256 b, XCD-grouped), block = 256 (4 waves, 2x2)
__global__ void __launch_bounds__(256, 2)
snn_proj_scan(const float* __restrict__ x, const float* __restrict__ W1,
              const float* __restrict__ b1, const float* __restrict__ betap,
              float* __restrict__ memT)
{
    __shared__ __align__(16) char smem[SMEM_BYTES];

    const int tid  = threadIdx.x;
    const int lane = tid & 63;
    const int wid  = tid >> 6;
    const int wm = wid >> 1, wn = wid & 1;      // wave tile: 64t x 64h
    const int g2 = lane >> 5, lr = lane & 31;   // 32x32 MFMA lane decomposition

    // XCD-grouping swizzle: all 8 h-tiles of a given b land on one XCD,
    // consecutive slots share b -> x tile stays L2-resident.
    const int lid  = blockIdx.x;
    const int slot = lid >> 3;
    const int b     = ((lid & 7) << 5) + (slot >> 3);
    const int hbase = (slot & 7) * BN;

    const float* __restrict__ xg = x  + (size_t)b * TT * CC;
    const float* __restrict__ wg = W1 + (size_t)hbase * CC;

    // staging: each thread loads 8 float4 of x and 8 of W per stage
    const int srow = tid >> 4;          // rows advance by 16 per p
    const int skq  = tid & 15;          // float4 within the 64-f32 k-chunk
    const float* xrow = xg + srow * CC + skq * 4;
    const float* wrow = wg + srow * CC + skq * 4;
    const int wbyte = (skq * 8) ^ ((srow & 7) << 4);   // swizzled low-7 bits

    // fragment addressing: A rows = t, B rows = h; same [row][k] f16 layout
    const int sw    = (lr & 7) << 4;
    const int arow0 = (wm * 64 +  0 + lr) * 128;
    const int arow1 = (wm * 64 + 32 + lr) * 128;
    const int brow0 = (wn * 64 +  0 + lr) * 128;
    const int brow1 = (wn * 64 + 32 + lr) * 128;

    f32x16 acc00 = {}, acc01 = {}, acc10 = {}, acc11 = {};

    float4 px[8], pw[8];
#pragma unroll
    for (int p = 0; p < 8; ++p) {
        px[p] = *(const float4*)(xrow + p * 16 * CC);
        pw[p] = *(const float4*)(wrow + p * 16 * CC);
    }

    for (int s = 0; s < NSTAGE; ++s) {
        // convert + swizzled LDS write of the prefetched stage
#pragma unroll
        for (int p = 0; p < 8; ++p) {
            const int byte = (srow + 16 * p) * 128 + wbyte;
            f16x4 hi, lo;
            cvt_split(px[p], &hi, &lo);
            *(f16x4*)(smem + XHI + byte) = hi;
            *(f16x4*)(smem + XLO + byte) = lo;
            cvt_split(pw[p], &hi, &lo);
            *(f16x4*)(smem + WHI + byte) = hi;
            *(f16x4*)(smem + WLO + byte) = lo;
        }
        __syncthreads();

        // issue next stage's global loads now; they complete under the MFMAs
        if (s + 1 < NSTAGE) {
            const int ko = (s + 1) * BK;
#pragma unroll
            for (int p = 0; p < 8; ++p) {
                px[p] = *(const float4*)(xrow + p * 16 * CC + ko);
                pw[p] = *(const float4*)(wrow + p * 16 * CC + ko);
            }
        }

#pragma unroll
        for (int ks = 0; ks < 4; ++ks) {
            const int off = ((ks << 5) | (g2 << 4)) ^ sw;
            const f16x8 ah0 = *(const f16x8*)(smem + XHI + arow0 + off);
            const f16x8 ah1 = *(const f16x8*)(smem + XHI + arow1 + off);
            const f16x8 al0 = *(const f16x8*)(smem + XLO + arow0 + off);
            const f16x8 al1 = *(const f16x8*)(smem + XLO + arow1 + off);
            const f16x8 bh0 = *(const f16x8*)(smem + WHI + brow0 + off);
            const f16x8 bh1 = *(const f16x8*)(smem + WHI + brow1 + off);
            const f16x8 bl0 = *(const f16x8*)(smem + WLO + brow0 + off);
            const f16x8 bl1 = *(const f16x8*)(smem + WLO + brow1 + off);

            acc00 = __builtin_amdgcn_mfma_f32_32x32x16_f16(ah0, bh0, acc00, 0, 0, 0);
            acc00 = __builtin_amdgcn_mfma_f32_32x32x16_f16(ah0, bl0, acc00, 0, 0, 0);
            acc00 = __builtin_amdgcn_mfma_f32_32x32x16_f16(al0, bh0, acc00, 0, 0, 0);

            acc01 = __builtin_amdgcn_mfma_f32_32x32x16_f16(ah0, bh1, acc01, 0, 0, 0);
            acc01 = __builtin_amdgcn_mfma_f32_32x32x16_f16(ah0, bl1, acc01, 0, 0, 0);
            acc01 = __builtin_amdgcn_mfma_f32_32x32x16_f16(al0, bh1, acc01, 0, 0, 0);

            acc10 = __builtin_amdgcn_mfma_f32_32x32x16_f16(ah1, bh0, acc10, 0, 0, 0);
            acc10 = __builtin_amdgcn_mfma_f32_32x32x16_f16(ah1, bl0, acc10, 0, 0, 0);
            acc10 = __builtin_amdgcn_mfma_f32_32x32x16_f16(al1, bh0, acc10, 0, 0, 0);

            acc11 = __builtin_amdgcn_mfma_f32_32x32x16_f16(ah1, bh1, acc11, 0, 0, 0);
            acc11 = __builtin_amdgcn_mfma_f32_32x32x16_f16(ah1, bl1, acc11, 0, 0, 0);
            acc11 = __builtin_amdgcn_mfma_f32_32x32x16_f16(al1, bh1, acc11, 0, 0, 0);
        }
        __syncthreads();
    }

    // Epilogue: acc -> transposed scan buffer sbuf[h][132] f32 (t contiguous).
    // C/D layout (m74/m101): col = lane&31, row = (reg&3) + 8*(reg>>2) + 4*(lane>>5)
#define ST_ACC(A, m, n) {                                                        \
        char* rp = smem + (wn * 64 + (n) * 32 + lr) * 528                        \
                        + (wm * 64 + (m) * 32 + 4 * g2) * 4;                     \
        *(float4*)(rp +  0) = make_float4(A[0],  A[1],  A[2],  A[3]);            \
        *(float4*)(rp + 32) = make_float4(A[4],  A[5],  A[6],  A[7]);            \
        *(float4*)(rp + 64) = make_float4(A[8],  A[9],  A[10], A[11]);           \
        *(float4*)(rp + 96) = make_float4(A[12], A[13], A[14], A[15]); }
    ST_ACC(acc00, 0, 0)
    ST_ACC(acc01, 0, 1)
    ST_ACC(acc10, 1, 0)
    ST_ACC(acc11, 1, 1)
#undef ST_ACC
    __syncthreads();

    // Sequential leaky scan over t (snntorch Leaky, reset=subtract, strict >)
    if (tid < BN) {
        const float beta_c = fminf(fmaxf(betap[0], 0.0f), 1.0f);
        const float b1h = b1[hbase + tid];
        const char* rp = smem + tid * 528;
        float mem = 0.0f;
#pragma unroll
        for (int q = 0; q < 32; ++q) {
            const float4 v = *(const float4*)(rp + 16 * q);
            float reset;
            reset = (mem > 1.0f) ? 1.0f : 0.0f; mem = beta_c * mem + (v.x + b1h) - reset;
            reset = (mem > 1.0f) ? 1.0f : 0.0f; mem = beta_c * mem + (v.y + b1h) - reset;
            reset = (mem > 1.0f) ? 1.0f : 0.0f; mem = beta_c * mem + (v.z + b1h) - reset;
            reset = (mem > 1.0f) ? 1.0f : 0.0f; mem = beta_c * mem + (v.w + b1h) - reset;
        }
        memT[(size_t)b * HIDN + hbase + tid] = mem;
    }
}

// Head: out[b,o] = memT[b,:] . Wh[o,:] + bh[o]
// grid = 64 blocks x 4 b-rows, 192 threads (2 groups x 96 o)
__global__ void __launch_bounds__(192)
snn_head(const float* __restrict__ memT, const float* __restrict__ Wh,
         const float* __restrict__ bh, float* __restrict__ out)
{
    __shared__ __align__(16) float ms[4 * HIDN];
    const int tid = threadIdx.x;
    const int bbase = blockIdx.x * 4;
    const float4* src = (const float4*)(memT + (size_t)bbase * HIDN);
    for (int i = tid; i < HIDN; i += 192)     // 1024 float4 = 4 rows
        ((float4*)ms)[i] = src[i];
    __syncthreads();

    const int o = tid % 96, grp = tid / 96;
    const float4* wr = (const float4*)(Wh + (size_t)o * HIDN);
    const float4* m0 = (const float4*)(ms + (grp * 2 + 0) * HIDN);
    const float4* m1 = (const float4*)(ms + (grp * 2 + 1) * HIDN);
    float a0 = 0.f, a1 = 0.f;
    for (int q = 0; q < HIDN / 4; ++q) {
        const float4 w = wr[q];
        const float4 u = m0[q];
        const float4 v = m1[q];
        a0 = fmaf(w.x, u.x, fmaf(w.y, u.y, fmaf(w.z, u.z, fmaf(w.w, u.w, a0))));
        a1 = fmaf(w.x, v.x, fmaf(w.y, v.y, fmaf(w.z, v.z, fmaf(w.w, v.w, a1))));
    }
    const float bo = bh[o];
    out[(size_t)(bbase + grp * 2 + 0) * HORN + o] = a0 + bo;
    out[(size_t)(bbase + grp * 2 + 1) * HORN + o] = a1 + bo;
}

extern "C" void kernel_launch(void* const* d_in, const int* in_sizes, int n_in,
                              void* d_out, int out_size, void* d_ws, size_t ws_size,
                              hipStream_t stream)
{
    (void)in_sizes; (void)n_in; (void)out_size; (void)ws_size;
    const float* x    = (const float*)d_in[0];
    const float* W1   = (const float*)d_in[1];
    const float* b1   = (const float*)d_in[2];
    const float* Wh   = (const float*)d_in[3];
    const float* bh   = (const float*)d_in[4];
    const float* beta = (const float*)d_in[5];

    float* memT = (float*)d_ws;   // [B, HID] f32 = 1 MB scratch

    snn_proj_scan<<<2048, 256, 0, stream>>>(x, W1, b1, beta, memT);
    snn_head<<<64, 192, 0, stream>>>(memT, Wh, bh, (float*)d_out);
}

// Round 3
// 213.241 us; speedup vs baseline: 2.3465x; 1.1137x over previous
//
#include <hip/hip_runtime.h>

#define TT 128
#define CC 512
#define HIDN 1024
#define HORN 96
#define NB 256
#define BN 128
#define BK 64
#define NSTAGE 8

typedef _Float16 f16x8 __attribute__((ext_vector_type(8)));
typedef _Float16 f16x4 __attribute__((ext_vector_type(4)));
typedef float f32x16 __attribute__((ext_vector_type(16)));

// LDS: 4 staging tiles [128 rows][64 f16 = 128 B], XOR-swizzled in 16B slots.
// Epilogue overlays the whole 64 KB as scan buffer [128 h][128 t] f32, slot-swizzled.
#define XHI 0
#define XLO 16384
#define WHI 32768
#define WLO 49152
#define SMEM_BYTES 65536

// fp16 two-term split: v = hi + lo, |err| ~ 2^-22 * |v|
__device__ __forceinline__ void cvt_split(const float4 v, f16x4* hi, f16x4* lo) {
    auto h01 = __builtin_amdgcn_cvt_pkrtz(v.x, v.y);
    auto h23 = __builtin_amdgcn_cvt_pkrtz(v.z, v.w);
    auto l01 = __builtin_amdgcn_cvt_pkrtz(v.x - (float)h01.x, v.y - (float)h01.y);
    auto l23 = __builtin_amdgcn_cvt_pkrtz(v.z - (float)h23.x, v.w - (float)h23.y);
    *hi = (f16x4){(_Float16)h01.x, (_Float16)h01.y, (_Float16)h23.x, (_Float16)h23.y};
    *lo = (f16x4){(_Float16)l01.x, (_Float16)l01.y, (_Float16)l23.x, (_Float16)l23.y};
}

__device__ __forceinline__ void gload16(const void* g, void* l) {
    __builtin_amdgcn_global_load_lds(
        (const __attribute__((address_space(1))) unsigned int*)g,
        (__attribute__((address_space(3))) unsigned int*)l, 16, 0, 0);
}

// Prologue: split W1 f32 -> whi/wlo f16 (once; removes x256-redundant per-block cvt)
__global__ void __launch_bounds__(256)
snn_cvtw(const float* __restrict__ W1, f16x4* __restrict__ whi, f16x4* __restrict__ wlo)
{
    const int i = blockIdx.x * 256 + threadIdx.x;   // float4 index, 131072 total
    const float4 v = ((const float4*)W1)[i];
    f16x4 hi, lo;
    cvt_split(v, &hi, &lo);
    whi[i] = hi;
    wlo[i] = lo;
}

// Fused: proj = x @ W1^T (split-f16 MFMA, 3 products) then leaky scan -> memT[b,h]
// grid = 2048 (XCD-grouped: 8 h-tiles x 256 b), block = 256 (4 waves, 2x2)
__global__ void __launch_bounds__(256, 2)
snn_proj_scan(const float* __restrict__ x, const _Float16* __restrict__ whi_g,
              const _Float16* __restrict__ wlo_g, const float* __restrict__ b1,
              const float* __restrict__ betap, float* __restrict__ memT)
{
    __shared__ __align__(16) char smem[SMEM_BYTES];

    const int tid  = threadIdx.x;
    const int lane = tid & 63;
    const int wid  = tid >> 6;
    const int wm = wid >> 1, wn = wid & 1;      // wave tile: 64t x 64h
    const int g2 = lane >> 5, lr = lane & 31;   // 32x32 MFMA lane decomposition

    // XCD-grouping swizzle: the 8 h-tiles of one b land on one XCD -> x L2-resident
    const int lid  = blockIdx.x;
    const int slot = lid >> 3;
    const int b     = ((lid & 7) << 5) + (slot >> 3);
    const int hbase = (slot & 7) * BN;

    const float* __restrict__ xg = x + (size_t)b * TT * CC;

    // x staging: each thread loads 8 float4 per stage, converts, swizzled ds_write
    const int srow = tid >> 4;                  // +16 per p
    const int skq  = tid & 15;
    const float* xrow = xg + srow * CC + skq * 4;
    const int wbyte = (skq * 8) ^ ((srow & 7) << 4);

    // W staging via global_load_lds: wave w covers chunks w*4..w*4+3 (1 KB each;
    // chunk = 8 rows x 8 slots). Linear LDS dest; source pre-swizzled so that
    // LDS[row][slot] = G[row][slot ^ (row&7)] (rule #21: both-sides-or-neither).
    const int wrow0  = lane >> 3;                        // row within chunk (= row&7)
    const int wslotb = ((lane & 7) ^ wrow0) * 16;
    const char* whsrc = (const char*)whi_g + ((size_t)(hbase + wrow0) * CC) * 2 + wslotb;
    const char* wlsrc = (const char*)wlo_g + ((size_t)(hbase + wrow0) * CC) * 2 + wslotb;

    // fragment addressing (A rows = t, B rows = h; [row][128B] layout, slot-swizzled)
    const int sw    = (lr & 7) << 4;
    const int arow0 = (wm * 64 +  0 + lr) * 128;
    const int arow1 = (wm * 64 + 32 + lr) * 128;
    const int brow0 = (wn * 64 +  0 + lr) * 128;
    const int brow1 = (wn * 64 + 32 + lr) * 128;

    f32x16 acc00 = {}, acc01 = {}, acc10 = {}, acc11 = {};

    float4 px[8];
#pragma unroll
    for (int p = 0; p < 8; ++p) px[p] = *(const float4*)(xrow + p * 16 * CC);

    for (int s = 0; s < NSTAGE; ++s) {
        // 1) issue W gload_lds (latency hides under x cvt; pre-barrier vmcnt drains)
#pragma unroll
        for (int c = 0; c < 4; ++c) {
            const int chunk = wid * 4 + c;
            const size_t go = (size_t)chunk * (8 * CC * 2) + (size_t)s * (BK * 2);
            gload16(whsrc + go, smem + WHI + chunk * 1024);
            gload16(wlsrc + go, smem + WLO + chunk * 1024);
        }
        // 2) convert + swizzled LDS write of the prefetched x stage
#pragma unroll
        for (int p = 0; p < 8; ++p) {
            const int byte = (srow + 16 * p) * 128 + wbyte;
            f16x4 hi, lo;
            cvt_split(px[p], &hi, &lo);
            *(f16x4*)(smem + XHI + byte) = hi;
            *(f16x4*)(smem + XLO + byte) = lo;
        }
        __syncthreads();

        // 3) issue next stage's x global loads; they complete under the MFMAs
        if (s + 1 < NSTAGE) {
            const int ko = (s + 1) * BK;
#pragma unroll
            for (int p = 0; p < 8; ++p)
                px[p] = *(const float4*)(xrow + p * 16 * CC + ko);
        }

        // 4) MFMA: 48 per wave per stage (3 split-products x 4 frag pairs x 4 ks)
#pragma unroll
        for (int ks = 0; ks < 4; ++ks) {
            const int off = ((ks << 5) | (g2 << 4)) ^ sw;
            const f16x8 ah0 = *(const f16x8*)(smem + XHI + arow0 + off);
            const f16x8 ah1 = *(const f16x8*)(smem + XHI + arow1 + off);
            const f16x8 al0 = *(const f16x8*)(smem + XLO + arow0 + off);
            const f16x8 al1 = *(const f16x8*)(smem + XLO + arow1 + off);
            const f16x8 bh0 = *(const f16x8*)(smem + WHI + brow0 + off);
            const f16x8 bh1 = *(const f16x8*)(smem + WHI + brow1 + off);
            const f16x8 bl0 = *(const f16x8*)(smem + WLO + brow0 + off);
            const f16x8 bl1 = *(const f16x8*)(smem + WLO + brow1 + off);

            acc00 = __builtin_amdgcn_mfma_f32_32x32x16_f16(ah0, bh0, acc00, 0, 0, 0);
            acc00 = __builtin_amdgcn_mfma_f32_32x32x16_f16(ah0, bl0, acc00, 0, 0, 0);
            acc00 = __builtin_amdgcn_mfma_f32_32x32x16_f16(al0, bh0, acc00, 0, 0, 0);

            acc01 = __builtin_amdgcn_mfma_f32_32x32x16_f16(ah0, bh1, acc01, 0, 0, 0);
            acc01 = __builtin_amdgcn_mfma_f32_32x32x16_f16(ah0, bl1, acc01, 0, 0, 0);
            acc01 = __builtin_amdgcn_mfma_f32_32x32x16_f16(al0, bh1, acc01, 0, 0, 0);

            acc10 = __builtin_amdgcn_mfma_f32_32x32x16_f16(ah1, bh0, acc10, 0, 0, 0);
            acc10 = __builtin_amdgcn_mfma_f32_32x32x16_f16(ah1, bl0, acc10, 0, 0, 0);
            acc10 = __builtin_amdgcn_mfma_f32_32x32x16_f16(al1, bh0, acc10, 0, 0, 0);

            acc11 = __builtin_amdgcn_mfma_f32_32x32x16_f16(ah1, bh1, acc11, 0, 0, 0);
            acc11 = __builtin_amdgcn_mfma_f32_32x32x16_f16(ah1, bl1, acc11, 0, 0, 0);
            acc11 = __builtin_amdgcn_mfma_f32_32x32x16_f16(al1, bh1, acc11, 0, 0, 0);
        }
        __syncthreads();
    }

    // Epilogue: acc -> scan buffer [128 h][128 t] f32, 16B-slot XOR swizzle
    // (slot ^= row&31, bijective; spreads both stores and reads over all 32 slots).
    // C/D layout: col = lane&31 (h), row t = (reg&3) + 8*(reg>>2) + 4*(lane>>5)
#define ST_ACC(A, m, n) {                                                        \
        const int row   = wn * 64 + (n) * 32 + lr;                               \
        const int sbase = wm * 16 + (m) * 8 + g2;                                \
        const int rs    = row & 31;                                              \
        char* rb = smem + row * 512;                                             \
        *(float4*)(rb + (((sbase + 0) ^ rs) * 16)) = make_float4(A[0],  A[1],  A[2],  A[3]);  \
        *(float4*)(rb + (((sbase + 2) ^ rs) * 16)) = make_float4(A[4],  A[5],  A[6],  A[7]);  \
        *(float4*)(rb + (((sbase + 4) ^ rs) * 16)) = make_float4(A[8],  A[9],  A[10], A[11]); \
        *(float4*)(rb + (((sbase + 6) ^ rs) * 16)) = make_float4(A[12], A[13], A[14], A[15]); }
    ST_ACC(acc00, 0, 0)
    ST_ACC(acc01, 0, 1)
    ST_ACC(acc10, 1, 0)
    ST_ACC(acc11, 1, 1)
#undef ST_ACC
    __syncthreads();

    // Sequential leaky scan over t (snntorch Leaky, reset=subtract, strict >)
    if (tid < BN) {
        const float beta_c = fminf(fmaxf(betap[0], 0.0f), 1.0f);
        const float b1h = b1[hbase + tid];
        const char* rb = smem + tid * 512;
        const int rs = tid & 31;
        float mem = 0.0f;
#pragma unroll
        for (int q = 0; q < 32; ++q) {
            const float4 v = *(const float4*)(rb + ((q ^ rs) * 16));
            float reset;
            reset = (mem > 1.0f) ? 1.0f : 0.0f; mem = beta_c * mem + (v.x + b1h) - reset;
            reset = (mem > 1.0f) ? 1.0f : 0.0f; mem = beta_c * mem + (v.y + b1h) - reset;
            reset = (mem > 1.0f) ? 1.0f : 0.0f; mem = beta_c * mem + (v.z + b1h) - reset;
            reset = (mem > 1.0f) ? 1.0f : 0.0f; mem = beta_c * mem + (v.w + b1h) - reset;
        }
        memT[(size_t)b * HIDN + hbase + tid] = mem;
    }
}

// Head: out[b,o] = memT[b,:] . Wh[o,:] + bh[o]
// grid = 256 (one per b), 256 threads; wave-per-output, lanes along h (coalesced Wh)
__global__ void __launch_bounds__(256)
snn_head(const float* __restrict__ memT, const float* __restrict__ Wh,
         const float* __restrict__ bh, float* __restrict__ out)
{
    __shared__ __align__(16) float ms[HIDN];
    const int b   = blockIdx.x;
    const int tid = threadIdx.x;
    ((float4*)ms)[tid] = ((const float4*)(memT + (size_t)b * HIDN))[tid];
    __syncthreads();

    const int lane = tid & 63, wid = tid >> 6;
    for (int o = wid; o < HORN; o += 4) {
        const float4* wr = (const float4*)(Wh + (size_t)o * HIDN);
        float a = 0.0f;
#pragma unroll
        for (int q = 0; q < 4; ++q) {
            const float4 w = wr[q * 64 + lane];
            const float4 m = ((const float4*)ms)[q * 64 + lane];
            a = fmaf(w.x, m.x, fmaf(w.y, m.y, fmaf(w.z, m.z, fmaf(w.w, m.w, a))));
        }
#pragma unroll
        for (int d = 32; d; d >>= 1) a += __shfl_xor(a, d);
        if (lane == 0) out[(size_t)b * HORN + o] = a + bh[o];
    }
}

extern "C" void kernel_launch(void* const* d_in, const int* in_sizes, int n_in,
                              void* d_out, int out_size, void* d_ws, size_t ws_size,
                              hipStream_t stream)
{
    (void)in_sizes; (void)n_in; (void)out_size; (void)ws_size;
    const float* x    = (const float*)d_in[0];
    const float* W1   = (const float*)d_in[1];
    const float* b1   = (const float*)d_in[2];
    const float* Wh   = (const float*)d_in[3];
    const float* bh   = (const float*)d_in[4];
    const float* beta = (const float*)d_in[5];

    // ws layout: whi [1 MB] | wlo [1 MB] | memT [1 MB]
    char* ws = (char*)d_ws;
    _Float16* whi = (_Float16*)(ws);
    _Float16* wlo = (_Float16*)(ws + (1 << 20));
    float*    memT = (float*)(ws + (2 << 20));

    snn_cvtw<<<512, 256, 0, stream>>>(W1, (f16x4*)whi, (f16x4*)wlo);
    snn_proj_scan<<<2048, 256, 0, stream>>>(x, whi, wlo, b1, beta, memT);
    snn_head<<<NB, 256, 0, stream>>>(memT, Wh, bh, (float*)d_out);
}

// Round 4
// 212.422 us; speedup vs baseline: 2.3556x; 1.0039x over previous
//
#include <hip/hip_runtime.h>

#define TT 128
#define CC 512
#define HIDN 1024
#define HORN 96
#define NB 256
#define BN 128
#define BK 64
#define NSTAGE 8

typedef _Float16 f16x8 __attribute__((ext_vector_type(8)));
typedef _Float16 f16x4 __attribute__((ext_vector_type(4)));
typedef float f32x16 __attribute__((ext_vector_type(16)));

// LDS: 4 staging tiles [128 rows][64 f16 = 128 B], XOR-swizzled in 16B slots.
// Epilogue overlays the whole 64 KB as scan buffer [128 h][128 t] f32, slot-swizzled.
#define XHI 0
#define XLO 16384
#define WHI 32768
#define WLO 49152
#define SMEM_BYTES 65536

// fp16 two-term split: v = hi + lo, |err| ~ 2^-22 * |v|
__device__ __forceinline__ void cvt_split(const float4 v, f16x4* hi, f16x4* lo) {
    auto h01 = __builtin_amdgcn_cvt_pkrtz(v.x, v.y);
    auto h23 = __builtin_amdgcn_cvt_pkrtz(v.z, v.w);
    auto l01 = __builtin_amdgcn_cvt_pkrtz(v.x - (float)h01.x, v.y - (float)h01.y);
    auto l23 = __builtin_amdgcn_cvt_pkrtz(v.z - (float)h23.x, v.w - (float)h23.y);
    *hi = (f16x4){(_Float16)h01.x, (_Float16)h01.y, (_Float16)h23.x, (_Float16)h23.y};
    *lo = (f16x4){(_Float16)l01.x, (_Float16)l01.y, (_Float16)l23.x, (_Float16)l23.y};
}

__device__ __forceinline__ void gload16(const void* g, void* l) {
    __builtin_amdgcn_global_load_lds(
        (const __attribute__((address_space(1))) unsigned int*)g,
        (__attribute__((address_space(3))) unsigned int*)l, 16, 0, 0);
}

// Prologue: split W1 f32 -> whi/wlo f16 (once), and init out[b,o] = bh[o]
// (out must be STORED before the head's atomicAdds; stream order guarantees it)
__global__ void __launch_bounds__(256)
snn_cvtw(const float* __restrict__ W1, f16x4* __restrict__ whi, f16x4* __restrict__ wlo,
         const float* __restrict__ bh, float* __restrict__ out)
{
    const int i = blockIdx.x * 256 + threadIdx.x;   // float4 index, 131072 total
    const float4 v = ((const float4*)W1)[i];
    f16x4 hi, lo;
    cvt_split(v, &hi, &lo);
    whi[i] = hi;
    wlo[i] = lo;
    if (i < NB * HORN) out[i] = bh[i % HORN];       // 24576 = 96 blocks' worth
}

// Fused: proj = x @ W1^T (split-f16 MFMA, 3 products) then leaky scan -> memT[b,h]
// grid = 2048 (XCD-grouped: 8 h-tiles x 256 b), block = 256 (4 waves, 2x2)
__global__ void __launch_bounds__(256, 2)
snn_proj_scan(const float* __restrict__ x, const _Float16* __restrict__ whi_g,
              const _Float16* __restrict__ wlo_g, const float* __restrict__ b1,
              const float* __restrict__ betap, float* __restrict__ memT)
{
    __shared__ __align__(16) char smem[SMEM_BYTES];

    const int tid  = threadIdx.x;
    const int lane = tid & 63;
    const int wid  = tid >> 6;
    const int wm = wid >> 1, wn = wid & 1;      // wave tile: 64t x 64h
    const int g2 = lane >> 5, lr = lane & 31;   // 32x32 MFMA lane decomposition

    // XCD-grouping swizzle: the 8 h-tiles of one b land on one XCD -> x L2-resident
    const int lid  = blockIdx.x;
    const int slot = lid >> 3;
    const int b     = ((lid & 7) << 5) + (slot >> 3);
    const int hbase = (slot & 7) * BN;

    const float* __restrict__ xg = x + (size_t)b * TT * CC;

    // x staging: each thread loads 8 float4 per stage, converts, swizzled ds_write
    const int srow = tid >> 4;                  // +16 per p
    const int skq  = tid & 15;
    const float* xrow = xg + srow * CC + skq * 4;
    const int wbyte = (skq * 8) ^ ((srow & 7) << 4);

    // W staging via global_load_lds (linear dest + inverse-swizzled source, rule #21)
    const int wrow0  = lane >> 3;
    const int wslotb = ((lane & 7) ^ wrow0) * 16;
    const char* whsrc = (const char*)whi_g + ((size_t)(hbase + wrow0) * CC) * 2 + wslotb;
    const char* wlsrc = (const char*)wlo_g + ((size_t)(hbase + wrow0) * CC) * 2 + wslotb;

    // fragment addressing (A rows = t, B rows = h; [row][128B] layout, slot-swizzled)
    const int sw    = (lr & 7) << 4;
    const int arow0 = (wm * 64 +  0 + lr) * 128;
    const int arow1 = (wm * 64 + 32 + lr) * 128;
    const int brow0 = (wn * 64 +  0 + lr) * 128;
    const int brow1 = (wn * 64 + 32 + lr) * 128;

    f32x16 acc00 = {}, acc01 = {}, acc10 = {}, acc11 = {};

    float4 px[8];
#pragma unroll
    for (int p = 0; p < 8; ++p) px[p] = *(const float4*)(xrow + p * 16 * CC);

// two named fragment register sets, rolling double-buffer across ks
#define FRAG_SET(P) f16x8 ah0##P, ah1##P, al0##P, al1##P, bh0##P, bh1##P, bl0##P, bl1##P;
#define FRAG_LOAD(P, KS) { \
        const int off = (((KS) << 5) | (g2 << 4)) ^ sw; \
        ah0##P = *(const f16x8*)(smem + XHI + arow0 + off); \
        ah1##P = *(const f16x8*)(smem + XHI + arow1 + off); \
        al0##P = *(const f16x8*)(smem + XLO + arow0 + off); \
        al1##P = *(const f16x8*)(smem + XLO + arow1 + off); \
        bh0##P = *(const f16x8*)(smem + WHI + brow0 + off); \
        bh1##P = *(const f16x8*)(smem + WHI + brow1 + off); \
        bl0##P = *(const f16x8*)(smem + WLO + brow0 + off); \
        bl1##P = *(const f16x8*)(smem + WLO + brow1 + off); }
// 12 MFMAs, interleaved across the 4 independent acc chains (dep spacing 4*8cy);
// per-acc product order (hh, hl, lh) matches rounds 2/3 -> bit-identical result
#define FRAG_MFMA(P) \
        acc00 = __builtin_amdgcn_mfma_f32_32x32x16_f16(ah0##P, bh0##P, acc00, 0, 0, 0); \
        acc01 = __builtin_amdgcn_mfma_f32_32x32x16_f16(ah0##P, bh1##P, acc01, 0, 0, 0); \
        acc10 = __builtin_amdgcn_mfma_f32_32x32x16_f16(ah1##P, bh0##P, acc10, 0, 0, 0); \
        acc11 = __builtin_amdgcn_mfma_f32_32x32x16_f16(ah1##P, bh1##P, acc11, 0, 0, 0); \
        acc00 = __builtin_amdgcn_mfma_f32_32x32x16_f16(ah0##P, bl0##P, acc00, 0, 0, 0); \
        acc01 = __builtin_amdgcn_mfma_f32_32x32x16_f16(ah0##P, bl1##P, acc01, 0, 0, 0); \
        acc10 = __builtin_amdgcn_mfma_f32_32x32x16_f16(ah1##P, bl0##P, acc10, 0, 0, 0); \
        acc11 = __builtin_amdgcn_mfma_f32_32x32x16_f16(ah1##P, bl1##P, acc11, 0, 0, 0); \
        acc00 = __builtin_amdgcn_mfma_f32_32x32x16_f16(al0##P, bh0##P, acc00, 0, 0, 0); \
        acc01 = __builtin_amdgcn_mfma_f32_32x32x16_f16(al0##P, bh1##P, acc01, 0, 0, 0); \
        acc10 = __builtin_amdgcn_mfma_f32_32x32x16_f16(al1##P, bh0##P, acc10, 0, 0, 0); \
        acc11 = __builtin_amdgcn_mfma_f32_32x32x16_f16(al1##P, bh1##P, acc11, 0, 0, 0);

    for (int s = 0; s < NSTAGE; ++s) {
        // 1) issue W gload_lds (latency hides under x cvt; pre-barrier vmcnt drains)
#pragma unroll
        for (int c = 0; c < 4; ++c) {
            const int chunk = wid * 4 + c;
            const size_t go = (size_t)chunk * (8 * CC * 2) + (size_t)s * (BK * 2);
            gload16(whsrc + go, smem + WHI + chunk * 1024);
            gload16(wlsrc + go, smem + WLO + chunk * 1024);
        }
        // 2) convert + swizzled LDS write of the prefetched x stage
#pragma unroll
        for (int p = 0; p < 8; ++p) {
            const int byte = (srow + 16 * p) * 128 + wbyte;
            f16x4 hi, lo;
            cvt_split(px[p], &hi, &lo);
            *(f16x4*)(smem + XHI + byte) = hi;
            *(f16x4*)(smem + XLO + byte) = lo;
        }
        __syncthreads();

        // 3) issue next stage's x global loads; they complete under the MFMAs
        if (s + 1 < NSTAGE) {
            const int ko = (s + 1) * BK;
#pragma unroll
            for (int p = 0; p < 8; ++p)
                px[p] = *(const float4*)(xrow + p * 16 * CC + ko);
        }

        // 4) rolling fragment prefetch + interleaved MFMA burst (hand pipeline)
        {
            FRAG_SET(A)
            FRAG_SET(B)
            FRAG_LOAD(A, 0)
            FRAG_LOAD(B, 1)
            __builtin_amdgcn_s_setprio(1);
            FRAG_MFMA(A)
            FRAG_LOAD(A, 2)
            FRAG_MFMA(B)
            FRAG_LOAD(B, 3)
            FRAG_MFMA(A)
            FRAG_MFMA(B)
            __builtin_amdgcn_s_setprio(0);
        }
        __syncthreads();
    }
#undef FRAG_SET
#undef FRAG_LOAD
#undef FRAG_MFMA

    // Epilogue: acc -> scan buffer [128 h][128 t] f32, 16B-slot XOR swizzle.
    // C/D layout: col = lane&31 (h), row t = (reg&3) + 8*(reg>>2) + 4*(lane>>5)
#define ST_ACC(A, m, n) {                                                        \
        const int row   = wn * 64 + (n) * 32 + lr;                               \
        const int sbase = wm * 16 + (m) * 8 + g2;                                \
        const int rs    = row & 31;                                              \
        char* rb = smem + row * 512;                                             \
        *(float4*)(rb + (((sbase + 0) ^ rs) * 16)) = make_float4(A[0],  A[1],  A[2],  A[3]);  \
        *(float4*)(rb + (((sbase + 2) ^ rs) * 16)) = make_float4(A[4],  A[5],  A[6],  A[7]);  \
        *(float4*)(rb + (((sbase + 4) ^ rs) * 16)) = make_float4(A[8],  A[9],  A[10], A[11]); \
        *(float4*)(rb + (((sbase + 6) ^ rs) * 16)) = make_float4(A[12], A[13], A[14], A[15]); }
    ST_ACC(acc00, 0, 0)
    ST_ACC(acc01, 0, 1)
    ST_ACC(acc10, 1, 0)
    ST_ACC(acc11, 1, 1)
#undef ST_ACC
    __syncthreads();

    // Sequential leaky scan over t (snntorch Leaky, reset=subtract, strict >)
    if (tid < BN) {
        const float beta_c = fminf(fmaxf(betap[0], 0.0f), 1.0f);
        const float b1h = b1[hbase + tid];
        const char* rb = smem + tid * 512;
        const int rs = tid & 31;
        float mem = 0.0f;
#pragma unroll
        for (int q = 0; q < 32; ++q) {
            const float4 v = *(const float4*)(rb + ((q ^ rs) * 16));
            float reset;
            reset = (mem > 1.0f) ? 1.0f : 0.0f; mem = beta_c * mem + (v.x + b1h) - reset;
            reset = (mem > 1.0f) ? 1.0f : 0.0f; mem = beta_c * mem + (v.y + b1h) - reset;
            reset = (mem > 1.0f) ? 1.0f : 0.0f; mem = beta_c * mem + (v.z + b1h) - reset;
            reset = (mem > 1.0f) ? 1.0f : 0.0f; mem = beta_c * mem + (v.w + b1h) - reset;
        }
        memT[(size_t)b * HIDN + hbase + tid] = mem;
    }
}

// Head: out[b,o] += memT[b, kc*64 : kc*64+64] . Wh[o, same] (bias pre-stored by cvtw)
// grid = (16 kchunks, 16 bgroups), block 256. Wh HBM/L2 traffic: 16 x 384 KB = 6 MB.
__global__ void __launch_bounds__(256)
snn_head(const float* __restrict__ memT, const float* __restrict__ Wh,
         float* __restrict__ out)
{
    __shared__ __align__(16) float ms[16][64];     // memT sub-tile, 4 KB
    __shared__ __align__(16) float ws[HORN][64];   // Wh sub-tile, 24 KB
    const int tid = threadIdx.x;
    const int kc = blockIdx.x, bg = blockIdx.y;
    const int kof = kc * 64;

    {   // stage memT[bg*16..+16)[kof..+64): 256 float4, one per thread
        const int row = tid >> 4, c4 = tid & 15;
        *(float4*)&ms[row][c4 * 4] =
            *(const float4*)(memT + (size_t)(bg * 16 + row) * HIDN + kof + c4 * 4);
    }
#pragma unroll
    for (int r = 0; r < 6; ++r) {   // stage Wh[0..96)[kof..+64): 1536 float4
        const int q = r * 256 + tid;
        const int row = q >> 4, c4 = q & 15;
        *(float4*)&ws[row][c4 * 4] =
            *(const float4*)(Wh + (size_t)row * HIDN + kof + c4 * 4);
    }
    __syncthreads();

#pragma unroll
    for (int r = 0; r < 6; ++r) {   // 1536 (b,o) partial dots, 6 per thread
        const int p = r * 256 + tid;
        const int bb = p / HORN, o = p % HORN;
        const float4* mv = (const float4*)&ms[bb][0];
        const float4* wv = (const float4*)&ws[o][0];
        float a = 0.0f;
#pragma unroll
        for (int q = 0; q < 16; ++q) {
            const float4 w = wv[q];
            const float4 m = mv[q];
            a = fmaf(w.x, m.x, fmaf(w.y, m.y, fmaf(w.z, m.z, fmaf(w.w, m.w, a))));
        }
        atomicAdd(out + (size_t)(bg * 16 + bb) * HORN + o, a);
    }
}

extern "C" void kernel_launch(void* const* d_in, const int* in_sizes, int n_in,
                              void* d_out, int out_size, void* d_ws, size_t ws_size,
                              hipStream_t stream)
{
    (void)in_sizes; (void)n_in; (void)out_size; (void)ws_size;
    const float* x    = (const float*)d_in[0];
    const float* W1   = (const float*)d_in[1];
    const float* b1   = (const float*)d_in[2];
    const float* Wh   = (const float*)d_in[3];
    const float* bh   = (const float*)d_in[4];
    const float* beta = (const float*)d_in[5];

    // ws layout: whi [1 MB] | wlo [1 MB] | memT [1 MB]
    char* ws = (char*)d_ws;
    _Float16* whi = (_Float16*)(ws);
    _Float16* wlo = (_Float16*)(ws + (1 << 20));
    float*    memT = (float*)(ws + (2 << 20));
    float*    out  = (float*)d_out;

    snn_cvtw<<<512, 256, 0, stream>>>(W1, (f16x4*)whi, (f16x4*)wlo, bh, out);
    snn_proj_scan<<<2048, 256, 0, stream>>>(x, whi, wlo, b1, beta, memT);
    snn_head<<<dim3(16, 16), 256, 0, stream>>>(memT, Wh, out);
}